// Round 7
// baseline (279.644 us; speedup 1.0000x reference)
//
#include <hip/hip_runtime.h>
#include <cmath>

// Outputs concatenated flat (all float32):
//   [0)      N*N*3 : dxyz_m
//   [N*N*3)  N*N   : buckets
//   [N*N*4)  N*N   : dscanid
//   [N*N*5)  N*N   : mask
//
// Four sequential kernels, each writing ONE region as a single linear stream
// (fill-like write front; no concurrent 36MiB-aliased streams). Each reuses
// the R2-proven compute structure: 4 j's per thread, vectorized j-side loads,
// wave-uniform i-side scalar loads. Mask math is recomputed per kernel
// (~60 VALU / 4 pairs — cheap vs the write-BW prize).

__device__ __forceinline__ float bucket_base(float v) {
    // x = v / RES (RES=0.5 -> exact *2)
    const float x  = v * 2.0f;
    const float xa = fabsf(x);
    if (xa <= 2.0f) {
        return 8.0f + rintf(x); // round-half-to-even like jnp.round
    }
    const float lr = logf(fmaxf(xa, 1e-6f) * 0.5f) / 2.0794415416798357f; // /log(8)
    const float sup = fminf(rintf(2.0f - 6.0f * lr), 8.0f);
    return 8.0f + ((x > 0.0f) ? sup : -sup);
}

// Mask + masked deltas for 4 consecutive pairs (i, j0..j0+3), j0 % 4 == 0.
// Identical numerics to the R2 kernel (absmax 0.0 verified).
__device__ __forceinline__ void quad_mask(
    const float* __restrict__ xyz, const int* __restrict__ grid,
    int i, int j0,
    float dxm[4], float dym[4], float dzm[4], bool mk[4],
    int jblk[4], int& blk_i, bool& any)
{
#pragma clang fp contract(off)
    const float xi = xyz[3*i+0], yi = xyz[3*i+1], zi = xyz[3*i+2];
    const int bat_i = grid[5*i+0]; blk_i = grid[5*i+1];
    const int c0i = grid[5*i+2], c1i = grid[5*i+3], c2i = grid[5*i+4];
    const int xci = (int)ceilf(xi/3.0f), yci = (int)ceilf(yi/3.0f);

    const float4* pv = reinterpret_cast<const float4*>(xyz + (size_t)3 * j0);
    const float4 p0 = pv[0], p1 = pv[1], p2 = pv[2];
    const int4* gv = reinterpret_cast<const int4*>(grid + (size_t)5 * j0);
    const int4 g0 = gv[0], g1 = gv[1], g2 = gv[2], g3 = gv[3], g4 = gv[4];

    const float jx[4]  = {p0.x, p0.w, p1.z, p2.y};
    const float jy[4]  = {p0.y, p1.x, p1.w, p2.z};
    const float jz[4]  = {p0.z, p1.y, p2.x, p2.w};
    const int   jbat[4] = {g0.x, g1.y, g2.z, g3.w};
    const int   jb[4]   = {g0.y, g1.z, g2.w, g4.x};
    const int   jc0[4]  = {g0.z, g1.w, g3.x, g4.y};
    const int   jc1[4]  = {g0.w, g2.x, g3.y, g4.z};
    const int   jc2[4]  = {g1.x, g2.y, g3.z, g4.w};

    any = false;
#pragma unroll
    for (int k = 0; k < 4; ++k) {
        const float dx = xi - jx[k];
        const float dy = yi - jy[k];
        const float dz = zi - jz[k];
        const bool batch_eq = (bat_i == jbat[k]);
        const bool block_le = (blk_i <= jb[k]);
        const int  cadj = max(max(abs(c0i - jc0[k]), abs(c1i - jc1[k])),
                              abs(c2i - jc2[k]));
        const bool forcekeep = (cadj <= 1) && (blk_i == jb[k]);
        const int xcj = (int)ceilf(jx[k] / 3.0f);
        const int ycj = (int)ceilf(jy[k] / 3.0f);
        const bool keep_coarse = max(abs(xci - xcj), abs(yci - ycj)) <= 1;
        const float d2 = dx * dx + dy * dy + dz * dz; // contract(off)
        const bool keepr = (d2 <= 9.0f);
        const bool m = batch_eq && block_le &&
                       (forcekeep || keep_coarse) && (forcekeep || keepr);
        mk[k] = m; any |= m;
        jblk[k] = jb[k];
        dxm[k] = m ? dx : 0.0f;
        dym[k] = m ? dy : 0.0f;
        dzm[k] = m ? dz : 0.0f;
    }
}

// ---- Kernel 1: dxyz_m (3 float4 per thread, single linear region) ----
__global__ __launch_bounds__(256) void k_dxyz(
    const float* __restrict__ xyz, const int* __restrict__ grid,
    float* __restrict__ dst, int N)
{
    const int jq = blockIdx.x * blockDim.x + threadIdx.x;
    const int j0 = jq << 2;
    const int i  = blockIdx.y;
    if (j0 >= N) return;

    float dx[4], dy[4], dz[4];
    bool mk[4]; int jblk[4], blk_i; bool any;
    quad_mask(xyz, grid, i, j0, dx, dy, dz, mk, jblk, blk_i, any);

    const size_t base = ((size_t)i * (size_t)N + (size_t)j0) * 3;
    float4* o = reinterpret_cast<float4*>(dst + base);
    o[0] = make_float4(dx[0], dy[0], dz[0], dx[1]);
    o[1] = make_float4(dy[1], dz[1], dx[2], dy[2]);
    o[2] = make_float4(dz[2], dx[3], dy[3], dz[3]);
}

// ---- Kernel 2: buckets (1 float4 per thread) ----
__global__ __launch_bounds__(256) void k_bkt(
    const float* __restrict__ xyz, const int* __restrict__ grid,
    float* __restrict__ dst, int N)
{
    const int jq = blockIdx.x * blockDim.x + threadIdx.x;
    const int j0 = jq << 2;
    const int i  = blockIdx.y;
    if (j0 >= N) return;

    float dx[4], dy[4], dz[4];
    bool mk[4]; int jblk[4], blk_i; bool any;
    quad_mask(xyz, grid, i, j0, dx, dy, dz, mk, jblk, blk_i, any);

    float4* o = reinterpret_cast<float4*>(dst + (size_t)i * (size_t)N + (size_t)j0);
    if (__ballot(any ? 1 : 0) == 0ULL) {
        *o = make_float4(0.0f, 0.0f, 0.0f, 0.0f);
        return;
    }
    float bf[4];
#pragma unroll
    for (int k = 0; k < 4; ++k) {
        if (mk[k]) {
            const float q0 = bucket_base(dx[k]);
            const float q1 = bucket_base(dy[k]);
            const float q2 = bucket_base(dz[k]);
            const float bsum = (289.0f * q0 + 17.0f * q1) + q2; // exact small ints
            bf[k] = (float)(int)bsum;
        } else {
            bf[k] = 0.0f;
        }
    }
    *o = make_float4(bf[0], bf[1], bf[2], bf[3]);
}

// ---- Kernel 3: dscanid (1 float4 per thread) ----
__global__ __launch_bounds__(256) void k_dsc(
    const float* __restrict__ xyz, const int* __restrict__ grid,
    float* __restrict__ dst, int N)
{
    const int jq = blockIdx.x * blockDim.x + threadIdx.x;
    const int j0 = jq << 2;
    const int i  = blockIdx.y;
    if (j0 >= N) return;

    float dx[4], dy[4], dz[4];
    bool mk[4]; int jblk[4], blk_i; bool any;
    quad_mask(xyz, grid, i, j0, dx, dy, dz, mk, jblk, blk_i, any);

    const int scan_i = blk_i >> 1;
    float df[4];
#pragma unroll
    for (int k = 0; k < 4; ++k)
        df[k] = mk[k] ? (float)((jblk[k] >> 1) - scan_i) : 0.0f;
    float4* o = reinterpret_cast<float4*>(dst + (size_t)i * (size_t)N + (size_t)j0);
    *o = make_float4(df[0], df[1], df[2], df[3]);
}

// ---- Kernel 4: mask (1 float4 per thread) ----
__global__ __launch_bounds__(256) void k_msk(
    const float* __restrict__ xyz, const int* __restrict__ grid,
    float* __restrict__ dst, int N)
{
    const int jq = blockIdx.x * blockDim.x + threadIdx.x;
    const int j0 = jq << 2;
    const int i  = blockIdx.y;
    if (j0 >= N) return;

    float dx[4], dy[4], dz[4];
    bool mk[4]; int jblk[4], blk_i; bool any;
    quad_mask(xyz, grid, i, j0, dx, dy, dz, mk, jblk, blk_i, any);

    float mf[4];
#pragma unroll
    for (int k = 0; k < 4; ++k)
        mf[k] = mk[k] ? 1.0f : 0.0f;
    float4* o = reinterpret_cast<float4*>(dst + (size_t)i * (size_t)N + (size_t)j0);
    *o = make_float4(mf[0], mf[1], mf[2], mf[3]);
}

extern "C" void kernel_launch(void* const* d_in, const int* in_sizes, int n_in,
                              void* d_out, int out_size, void* d_ws, size_t ws_size,
                              hipStream_t stream) {
    const float* xyz  = (const float*)d_in[0];
    const int*   grid = (const int*)d_in[1];
    float*       out  = (float*)d_out;
    const int N = in_sizes[0] / 3; // xyz is (N,3); N=3072, divisible by 4
    const size_t NN = (size_t)N * (size_t)N;

    const int BLOCK = 256;
    const int jquads = N / 4;
    dim3 gdim((jquads + BLOCK - 1) / BLOCK, N, 1);
    dim3 bdim(BLOCK, 1, 1);

    // Sequential single-stream writers, in ascending address order.
    k_dxyz<<<gdim, bdim, 0, stream>>>(xyz, grid, out,          N);
    k_bkt <<<gdim, bdim, 0, stream>>>(xyz, grid, out + 3 * NN, N);
    k_dsc <<<gdim, bdim, 0, stream>>>(xyz, grid, out + 4 * NN, N);
    k_msk <<<gdim, bdim, 0, stream>>>(xyz, grid, out + 5 * NN, N);
}

// Round 8
// 225.430 us; speedup vs baseline: 1.2405x; 1.2405x over previous
//
#include <hip/hip_runtime.h>
#include <cmath>

// Outputs concatenated flat (all float32):
//   [0)      N*N*3 : dxyz_m
//   [N*N*3)  N*N   : buckets
//   [N*N*4)  N*N   : dscanid
//   [N*N*5)  N*N   : mask
//
// Persistent-ish design: each block owns a fixed chunk of 1024 j's (256
// threads x 4 j). j-side data is loaded + preprocessed ONCE (incl. hoisted
// ceilf terms), then the block loops over IPB i's, issuing 6 dwordx4 stores
// per iteration -> long per-wave store bursts (fill-like), ~70 VALU between.
// Numerics identical to the R2 kernel (absmax 0.0 verified).

#define IPB 8  // i's per block; N % IPB == 0 for N=3072

__device__ __forceinline__ float bucket_base(float v) {
    // x = v / RES (RES=0.5 -> exact *2)
    const float x  = v * 2.0f;
    const float xa = fabsf(x);
    if (xa <= 2.0f) {
        return 8.0f + rintf(x); // round-half-to-even like jnp.round
    }
    const float lr = logf(fmaxf(xa, 1e-6f) * 0.5f) / 2.0794415416798357f; // /log(8)
    const float sup = fminf(rintf(2.0f - 6.0f * lr), 8.0f);
    return 8.0f + ((x > 0.0f) ? sup : -sup);
}

__global__ __launch_bounds__(256) void pair_iloop(
    const float* __restrict__ xyz, const int* __restrict__ grid,
    float* __restrict__ out, int N)
{
#pragma clang fp contract(off)
    const int jq = blockIdx.x * blockDim.x + threadIdx.x; // quad-of-j index
    const int j0 = jq << 2;
    if (j0 >= N) return;
    const int i0 = blockIdx.y * IPB;

    // ---- j-side: load + preprocess ONCE ----
    const float4* pv = reinterpret_cast<const float4*>(xyz + (size_t)3 * j0);
    const float4 p0 = pv[0], p1 = pv[1], p2 = pv[2];
    const int4* gv = reinterpret_cast<const int4*>(grid + (size_t)5 * j0);
    const int4 g0 = gv[0], g1 = gv[1], g2 = gv[2], g3 = gv[3], g4 = gv[4];

    const float jx[4]  = {p0.x, p0.w, p1.z, p2.y};
    const float jy[4]  = {p0.y, p1.x, p1.w, p2.z};
    const float jz[4]  = {p0.z, p1.y, p2.x, p2.w};
    const int   jbat[4] = {g0.x, g1.y, g2.z, g3.w};
    const int   jblk[4] = {g0.y, g1.z, g2.w, g4.x};
    const int   jc0[4]  = {g0.z, g1.w, g3.x, g4.y};
    const int   jc1[4]  = {g0.w, g2.x, g3.y, g4.z};
    const int   jc2[4]  = {g1.x, g2.y, g3.z, g4.w};
    int xcj[4], ycj[4];
#pragma unroll
    for (int k = 0; k < 4; ++k) {
        xcj[k] = (int)ceilf(jx[k] / 3.0f);  // hoisted: i-independent, same expr
        ycj[k] = (int)ceilf(jy[k] / 3.0f);
    }

    const size_t NN = (size_t)N * (size_t)N;

    for (int i = i0; i < i0 + IPB; ++i) {
        // i-side: block-uniform -> scalar loads
        const float xi = xyz[3 * i + 0];
        const float yi = xyz[3 * i + 1];
        const float zi = xyz[3 * i + 2];
        const int bat_i = grid[5 * i + 0];
        const int blk_i = grid[5 * i + 1];
        const int c0i = grid[5 * i + 2];
        const int c1i = grid[5 * i + 3];
        const int c2i = grid[5 * i + 4];
        const int xci = (int)ceilf(xi / 3.0f);
        const int yci = (int)ceilf(yi / 3.0f);
        const int scan_i = blk_i >> 1;

        float dxm[4], dym[4], dzm[4];
        bool mk[4];
        bool any = false;
#pragma unroll
        for (int k = 0; k < 4; ++k) {
            const float dx = xi - jx[k];
            const float dy = yi - jy[k];
            const float dz = zi - jz[k];
            const bool batch_eq = (bat_i == jbat[k]);
            const bool block_le = (blk_i <= jblk[k]);
            const int  cadj = max(max(abs(c0i - jc0[k]), abs(c1i - jc1[k])),
                                  abs(c2i - jc2[k]));
            const bool forcekeep = (cadj <= 1) && (blk_i == jblk[k]);
            const bool keep_coarse = max(abs(xci - xcj[k]), abs(yci - ycj[k])) <= 1;
            const float d2 = dx * dx + dy * dy + dz * dz; // contract(off)
            const bool keepr = (d2 <= 9.0f);
            const bool m = batch_eq && block_le &&
                           (forcekeep || keep_coarse) && (forcekeep || keepr);
            mk[k] = m; any |= m;
            dxm[k] = m ? dx : 0.0f;
            dym[k] = m ? dy : 0.0f;
            dzm[k] = m ? dz : 0.0f;
        }

        float bf[4], df[4], mf[4];
        if (__ballot(any ? 1 : 0) == 0ULL) {
#pragma unroll
            for (int k = 0; k < 4; ++k) { bf[k] = 0.0f; df[k] = 0.0f; mf[k] = 0.0f; }
        } else {
#pragma unroll
            for (int k = 0; k < 4; ++k) {
                if (mk[k]) {
                    const float q0 = bucket_base(dxm[k]);
                    const float q1 = bucket_base(dym[k]);
                    const float q2 = bucket_base(dzm[k]);
                    const float bsum = (289.0f * q0 + 17.0f * q1) + q2; // exact ints
                    bf[k] = (float)(int)bsum;
                    df[k] = (float)((jblk[k] >> 1) - scan_i);
                    mf[k] = 1.0f;
                } else {
                    bf[k] = 0.0f; df[k] = 0.0f; mf[k] = 0.0f;
                }
            }
        }

        const size_t base = (size_t)i * (size_t)N + (size_t)j0;
        float4* o_dxyz = reinterpret_cast<float4*>(out + 3 * base);
        o_dxyz[0] = make_float4(dxm[0], dym[0], dzm[0], dxm[1]);
        o_dxyz[1] = make_float4(dym[1], dzm[1], dxm[2], dym[2]);
        o_dxyz[2] = make_float4(dzm[2], dxm[3], dym[3], dzm[3]);
        *reinterpret_cast<float4*>(out + NN * 3 + base) = make_float4(bf[0], bf[1], bf[2], bf[3]);
        *reinterpret_cast<float4*>(out + NN * 4 + base) = make_float4(df[0], df[1], df[2], df[3]);
        *reinterpret_cast<float4*>(out + NN * 5 + base) = make_float4(mf[0], mf[1], mf[2], mf[3]);
    }
}

extern "C" void kernel_launch(void* const* d_in, const int* in_sizes, int n_in,
                              void* d_out, int out_size, void* d_ws, size_t ws_size,
                              hipStream_t stream) {
    const float* xyz  = (const float*)d_in[0];
    const int*   grid = (const int*)d_in[1];
    float*       out  = (float*)d_out;
    const int N = in_sizes[0] / 3; // xyz is (N,3); N=3072: %4==0, %IPB==0

    const int BLOCK = 256;
    const int jquads = N / 4;
    dim3 gdim((jquads + BLOCK - 1) / BLOCK, (N + IPB - 1) / IPB, 1);
    pair_iloop<<<gdim, dim3(BLOCK, 1, 1), 0, stream>>>(xyz, grid, out, N);
}